// Round 7
// baseline (520.870 us; speedup 1.0000x reference)
//
#include <hip/hip_runtime.h>
#include <math.h>

#define HDIM 2048   // hidden size H (== D_IN)
#define DOUT 1024
#define NLAYER 4
#define NBLK 1024   // fused kernel grid: 4 blocks/CU
#define TPB 256     // 4 waves: wave = gate

__device__ __forceinline__ float sigmoidf_(float x) {
    return 1.0f / (1.0f + expf(-x));
}

#define DOT4(acc, a, b) \
    acc = fmaf((a).x, (b).x, fmaf((a).y, (b).y, fmaf((a).z, (b).z, fmaf((a).w, (b).w, acc))))

// ---------------- Fused pipelined persistent kernel ----------------
// 1024 blocks x 256 threads (4 blocks/CU via launch_bounds(256,4), so the
// cooperative launch is guaranteed schedulable). Block b owns h-cells
// {2b,2b+1}; wave w computes gate w (i,f,g,o).
//
// Pipeline: each wave prefetches its ENTIRE per-layer W_ih share (16 x
// global_load_dwordx4 -> 64 VGPRs, 256 KB/CU in flight) BEFORE the layer
// sync, so the wait for h_{l-1} hides under queued HBM work.
// Sync: producers plain-store h then release-fetch_add cnt[l] (1 per block).
// Consumers: tid0 polls cnt (relaxed agent + s_sleep backoff, ONE thread per
// block), __syncthreads, then per-thread acquire fence (buffer_inv) and h is
// read with plain cached loads -- the exact machinery R4 proved correct.
__launch_bounds__(TPB, 4)
__global__ void lstm_fused_k(const float* __restrict__ x,
                             const float* __restrict__ h0,
                             const float* __restrict__ c0,
                             const float* __restrict__ Wih,
                             const float* __restrict__ Whh,
                             const float* __restrict__ bih,
                             const float* __restrict__ bhh,
                             const float* __restrict__ fcw,
                             const float* __restrict__ fcb,
                             float* __restrict__ out,
                             float* __restrict__ hbuf,   // [NLAYER*HDIM]
                             unsigned* __restrict__ cnt) // [64]: [l]=#blocks done
{
    __shared__ float sg[2][8];   // double-buffered gate values
    __shared__ float part[4];

    const int tid   = threadIdx.x;
    const int lane  = tid & 63;
    const int wave  = tid >> 6;    // gate index (i,f,g,o)
    const int blk   = blockIdx.x;
    const int cell0 = blk * 2;

    for (int l = 0; l < NLAYER; ++l) {
        const float* Wi   = Wih + (size_t)l * 4 * HDIM * HDIM;
        const float* Wh   = Whh + (size_t)l * 4 * HDIM * HDIM;
        const int    row0 = wave * HDIM + cell0;
        const float4* r0 = (const float4*)(Wi + (size_t)row0 * HDIM);
        const float4* r1 = (const float4*)(Wi + (size_t)(row0 + 1) * HDIM);

        // ---- 1) prefetch full W_ih share for this layer into VGPRs
        float4 w0[8], w1[8];
#pragma unroll
        for (int it = 0; it < 8; ++it) {
            w0[it] = r0[it * 64 + lane];
            w1[it] = r1[it * 64 + lane];
        }
        asm volatile("" ::: "memory");  // keep the loads above the wait

        // ---- 2) wait for h_{l-1}; hides under the in-flight weight stream.
        if (l > 0) {
            if (tid == 0) {
                while (__hip_atomic_load(&cnt[l - 1], __ATOMIC_RELAXED,
                                         __HIP_MEMORY_SCOPE_AGENT) < (unsigned)NBLK)
                    __builtin_amdgcn_s_sleep(32);
            }
            __syncthreads();
            __builtin_amdgcn_fence(__ATOMIC_ACQUIRE, "agent");  // inv stale L1/L2
        }

        // ---- 3) FMA sweep; h via plain cached loads (fresh after fence).
        //        Exact per-chunk W_hh skip: zero h_prev chunks contribute 0.
        const float4* hv4 = (const float4*)((l == 0) ? x : (hbuf + (size_t)(l - 1) * HDIM));
        const float4* hp4 = (const float4*)(h0 + l * HDIM);
        const float4* q0r = (const float4*)(Wh + (size_t)row0 * HDIM);
        const float4* q1r = (const float4*)(Wh + (size_t)(row0 + 1) * HDIM);

        float acc0 = 0.0f, acc1 = 0.0f;
#pragma unroll
        for (int it = 0; it < 8; ++it) {
            const float4 hv = hv4[it * 64 + lane];
            DOT4(acc0, w0[it], hv);
            DOT4(acc1, w1[it], hv);
            const float4 p = hp4[it * 64 + lane];
            if (p.x != 0.0f || p.y != 0.0f || p.z != 0.0f || p.w != 0.0f) {
                const float4 q0 = q0r[it * 64 + lane];
                const float4 q1 = q1r[it * 64 + lane];
                DOT4(acc0, q0, p);
                DOT4(acc1, q1, p);
            }
        }

        // ---- 4) gate combine across the wave
#pragma unroll
        for (int off = 32; off > 0; off >>= 1) {
            acc0 += __shfl_down(acc0, off, 64);
            acc1 += __shfl_down(acc1, off, 64);
        }
        if (lane == 0) {
            const float* bi = bih + (size_t)l * 4 * HDIM;
            const float* bh = bhh + (size_t)l * 4 * HDIM;
            sg[l & 1][wave * 2 + 0] = acc0 + bi[row0] + bh[row0];
            sg[l & 1][wave * 2 + 1] = acc1 + bi[row0 + 1] + bh[row0 + 1];
        }
        __syncthreads();

        // ---- 5) cell update + publish
        if (tid < 2) {
            const float iv = sg[l & 1][0 + tid];
            const float fv = sg[l & 1][2 + tid];
            const float gv = sg[l & 1][4 + tid];
            const float ov = sg[l & 1][6 + tid];
            const float cpv = c0[l * HDIM + cell0 + tid];
            const float cv = sigmoidf_(fv) * cpv + sigmoidf_(iv) * tanhf(gv);
            hbuf[(size_t)l * HDIM + cell0 + tid] = sigmoidf_(ov) * tanhf(cv);
        }
        if (tid == 0)  // release orders the wave's prior h stores
            __hip_atomic_fetch_add(&cnt[l], 1u, __ATOMIC_RELEASE,
                                   __HIP_MEMORY_SCOPE_AGENT);
        // sg is double-buffered; the next write to sg[l&1] is 2 layers away,
        // separated by the next layer's __syncthreads.
    }

    // ---- FC epilogue: out[blk] = fcw[blk,:] @ h3 + fcb[blk]
    {
        const float4* fr = (const float4*)(fcw + (size_t)blk * HDIM);
        float4 fw0 = fr[wave * 128 + lane];
        float4 fw1 = fr[wave * 128 + 64 + lane];
        asm volatile("" ::: "memory");

        if (tid == 0) {
            while (__hip_atomic_load(&cnt[NLAYER - 1], __ATOMIC_RELAXED,
                                     __HIP_MEMORY_SCOPE_AGENT) < (unsigned)NBLK)
                __builtin_amdgcn_s_sleep(32);
        }
        __syncthreads();
        __builtin_amdgcn_fence(__ATOMIC_ACQUIRE, "agent");

        const float4* h3 = (const float4*)(hbuf + (size_t)(NLAYER - 1) * HDIM);
        const float4 ha  = h3[wave * 128 + lane];
        const float4 hb2 = h3[wave * 128 + 64 + lane];
        float acc = 0.0f;
        DOT4(acc, fw0, ha);
        DOT4(acc, fw1, hb2);
#pragma unroll
        for (int off = 32; off > 0; off >>= 1) acc += __shfl_down(acc, off, 64);
        if (lane == 0) part[wave] = acc;
        __syncthreads();
        if (tid == 0)
            out[blk] = part[0] + part[1] + part[2] + part[3] + fcb[blk];
    }
}

// ---------------- Fallback path (proven 58 us, R1) ----------------
__launch_bounds__(256)
__global__ void lstm_layer_k(const float* __restrict__ Wi,
                             const float* __restrict__ Wh,
                             const float* __restrict__ bi,
                             const float* __restrict__ bh,
                             const float* __restrict__ hin,
                             const float* __restrict__ hprev,
                             const float* __restrict__ cprev,
                             float* __restrict__ hout)
{
    __shared__ float4 sh_in[HDIM / 4];
    __shared__ float  sgates[8];
    __shared__ int    nzflag;

    const int tid = threadIdx.x;
    if (tid == 0) nzflag = 0;
    __syncthreads();

    int nz = 0;
#pragma unroll
    for (int i = 0; i < 2; ++i) {
        const int idx = tid + i * 256;
        sh_in[idx] = ((const float4*)hin)[idx];
        float4 p = ((const float4*)hprev)[idx];
        if (p.x != 0.0f || p.y != 0.0f || p.z != 0.0f || p.w != 0.0f) nz = 1;
    }
    if (nz) nzflag = 1;
    __syncthreads();
    const int any_prev = nzflag;

    const int lane = tid & 63;
    const int wave = tid >> 6;
    const int cell0 = blockIdx.x * 2;
    const int row0 = wave * HDIM + cell0;

    const float4* r0 = (const float4*)(Wi + (size_t)row0 * HDIM);
    const float4* r1 = (const float4*)(Wi + (size_t)(row0 + 1) * HDIM);

    float acc0 = 0.0f, acc1 = 0.0f;
#pragma unroll
    for (int it = 0; it < 8; ++it) {
        const int idx = it * 64 + lane;
        const float4 a0 = r0[idx];
        const float4 a1 = r1[idx];
        const float4 hv = sh_in[idx];
        DOT4(acc0, a0, hv);
        DOT4(acc1, a1, hv);
    }

    if (any_prev) {
        const float4* q0 = (const float4*)(Wh + (size_t)row0 * HDIM);
        const float4* q1 = (const float4*)(Wh + (size_t)(row0 + 1) * HDIM);
        const float4* pv4 = (const float4*)hprev;
#pragma unroll
        for (int it = 0; it < 8; ++it) {
            const int idx = it * 64 + lane;
            const float4 a0 = q0[idx];
            const float4 a1 = q1[idx];
            const float4 pv = pv4[idx];
            DOT4(acc0, a0, pv);
            DOT4(acc1, a1, pv);
        }
    }

#pragma unroll
    for (int off = 32; off > 0; off >>= 1) {
        acc0 += __shfl_down(acc0, off, 64);
        acc1 += __shfl_down(acc1, off, 64);
    }
    if (lane == 0) {
        sgates[wave * 2 + 0] = acc0 + bi[row0] + bh[row0];
        sgates[wave * 2 + 1] = acc1 + bi[row0 + 1] + bh[row0 + 1];
    }
    __syncthreads();

    if (tid < 2) {
        const float iv = sgates[0 * 2 + tid];
        const float fv = sgates[1 * 2 + tid];
        const float gv = sgates[2 * 2 + tid];
        const float ov = sgates[3 * 2 + tid];
        const float cp = cprev[cell0 + tid];
        const float cv = sigmoidf_(fv) * cp + sigmoidf_(iv) * tanhf(gv);
        hout[cell0 + tid] = sigmoidf_(ov) * tanhf(cv);
    }
}

__launch_bounds__(256)
__global__ void fc_k(const float* __restrict__ W, const float* __restrict__ b,
                     const float* __restrict__ h, float* __restrict__ out)
{
    __shared__ float4 sh[HDIM / 4];
    const int tid = threadIdx.x;
#pragma unroll
    for (int i = 0; i < 2; ++i)
        sh[tid + i * 256] = ((const float4*)h)[tid + i * 256];
    __syncthreads();

    const int lane = tid & 63;
    const int wave = tid >> 6;
    const int row = blockIdx.x * 4 + wave;

    const float4* r = (const float4*)(W + (size_t)row * HDIM);
    float acc = 0.0f;
#pragma unroll
    for (int it = 0; it < 8; ++it) {
        const int idx = it * 64 + lane;
        const float4 a = r[idx];
        const float4 hv = sh[idx];
        DOT4(acc, a, hv);
    }
#pragma unroll
    for (int off = 32; off > 0; off >>= 1) acc += __shfl_down(acc, off, 64);
    if (lane == 0) out[row] = acc + b[row];
}

extern "C" void kernel_launch(void* const* d_in, const int* in_sizes, int n_in,
                              void* d_out, int out_size, void* d_ws, size_t ws_size,
                              hipStream_t stream) {
    const float* x   = (const float*)d_in[0];
    const float* h0  = (const float*)d_in[1];
    const float* c0  = (const float*)d_in[2];
    const float* Wih = (const float*)d_in[3];
    const float* Whh = (const float*)d_in[4];
    const float* bih = (const float*)d_in[5];
    const float* bhh = (const float*)d_in[6];
    const float* fcw = (const float*)d_in[7];
    const float* fcb = (const float*)d_in[8];
    float* out = (float*)d_out;

    float*    hbuf = (float*)d_ws;                          // 32 KiB
    unsigned* cnt  = (unsigned*)((char*)d_ws + 32 * 1024);  // 64 u32

    // Zero the per-layer counters each call (ws is poisoned / stale-replay).
    hipMemsetAsync(cnt, 0, 64 * sizeof(unsigned), stream);

    void* args[] = {(void*)&x, (void*)&h0, (void*)&c0, (void*)&Wih, (void*)&Whh,
                    (void*)&bih, (void*)&bhh, (void*)&fcw, (void*)&fcb,
                    (void*)&out, (void*)&hbuf, (void*)&cnt};
    hipError_t e = hipLaunchCooperativeKernel((void*)lstm_fused_k,
                                              dim3(NBLK), dim3(TPB),
                                              args, 0, stream);
    if (e != hipSuccess) {
        // Fallback: 5 sequential launches (identical math -> identical output).
        const size_t wstride = (size_t)4 * HDIM * HDIM;
        const int    bstride = 4 * HDIM;
        float* hb0 = hbuf;
        float* hb1 = hbuf + HDIM;
        const float* hin = x;
        float* houts[4] = {hb0, hb1, hb0, hb1};
        for (int l = 0; l < 4; ++l) {
            lstm_layer_k<<<HDIM / 2, 256, 0, stream>>>(
                Wih + (size_t)l * wstride, Whh + (size_t)l * wstride,
                bih + l * bstride, bhh + l * bstride,
                hin, h0 + l * HDIM, c0 + l * HDIM, houts[l]);
            hin = houts[l];
        }
        fc_k<<<DOUT / 4, 256, 0, stream>>>(fcw, fcb, hb1, out);
    }
}

// Round 9
// 112.078 us; speedup vs baseline: 4.6474x; 4.6474x over previous
//
#include <hip/hip_runtime.h>
#include <math.h>

#define HDIM 2048   // hidden size H (== D_IN)
#define DOUT 1024
#define NLAYER 4
#define NBLK 1024   // 4 blocks/CU
#define TPB 256     // 4 waves: wave = gate
#define NGRP 32     // arrival-tree groups (32 blocks each)
#define GRPSZ (NBLK / NGRP)

typedef __attribute__((address_space(1))) const unsigned glbu_t;
typedef __attribute__((address_space(3))) unsigned ldsu_t;

__device__ __forceinline__ float sigmoidf_(float x) {
    return 1.0f / (1.0f + expf(-x));
}

#define DOT4(acc, a, b) \
    acc = fmaf((a).x, (b).x, fmaf((a).y, (b).y, fmaf((a).z, (b).z, fmaf((a).w, (b).w, acc))))

// ---- LLC-coherent (L1/L2-bypassing) ops: NO fences, NO invalidates ----
__device__ __forceinline__ unsigned sc_load_u32(const unsigned* a) {
    unsigned v;
    asm volatile("global_load_dword %0, %1, off sc0 sc1\n\ts_waitcnt vmcnt(0)"
                 : "=v"(v) : "v"(a) : "memory");
    return v;
}
__device__ __forceinline__ void sc_store_f(float* a, float v) {
    asm volatile("global_store_dword %0, %1, off sc0 sc1\n\ts_waitcnt vmcnt(0)"
                 :: "v"(a), "v"(v) : "memory");
}
// 8 x float4 (one full 2048-float h vector share per thread), fresh from LLC.
// NOTE: global_* imm offset is 13-bit SIGNED (max +4095) -> use 2 base ptrs.
__device__ __forceinline__ void sc_load_h8(const float* base, int lane, float4 h[8]) {
    const char* p0 = (const char*)base + lane * 16;
    const char* p1 = p0 + 4096;
    asm volatile(
        "global_load_dwordx4 %0, %8, off sc0 sc1\n\t"
        "global_load_dwordx4 %1, %8, off offset:1024 sc0 sc1\n\t"
        "global_load_dwordx4 %2, %8, off offset:2048 sc0 sc1\n\t"
        "global_load_dwordx4 %3, %8, off offset:3072 sc0 sc1\n\t"
        "global_load_dwordx4 %4, %9, off sc0 sc1\n\t"
        "global_load_dwordx4 %5, %9, off offset:1024 sc0 sc1\n\t"
        "global_load_dwordx4 %6, %9, off offset:2048 sc0 sc1\n\t"
        "global_load_dwordx4 %7, %9, off offset:3072 sc0 sc1\n\t"
        "s_waitcnt vmcnt(0)"
        : "=v"(h[0]), "=v"(h[1]), "=v"(h[2]), "=v"(h[3]),
          "=v"(h[4]), "=v"(h[5]), "=v"(h[6]), "=v"(h[7])
        : "v"(p0), "v"(p1) : "memory");
    __builtin_amdgcn_sched_barrier(0);  // rule #18: pin consumers after waitcnt
}
__device__ __forceinline__ void sc_load_h2(const float* base, int tid, float4& a, float4& b) {
    const char* p0 = (const char*)base + tid * 16;
    const char* p1 = p0 + 4096;
    asm volatile(
        "global_load_dwordx4 %0, %2, off sc0 sc1\n\t"
        "global_load_dwordx4 %1, %3, off sc0 sc1\n\t"
        "s_waitcnt vmcnt(0)"
        : "=v"(a), "=v"(b) : "v"(p0), "v"(p1) : "memory");
    __builtin_amdgcn_sched_barrier(0);
}

// ---------------- Fused persistent kernel ----------------
// 1024 blocks x 256 threads. Block b owns h-cells {2b,2b+1}; wave w = gate w.
// Per layer l>=1: (1) stage half-K of this wave's 2 W_ih rows into LDS via
// global_load_lds (issued BEFORE the wait -> HBM streams during the wait);
// (2) tid0 polls root[l-1] (sc-load, sleep); (3) everyone sc-loads h (LLC,
// no fences); (4) FMA: half-K from LDS + half-K streamed from global;
// (5) gates -> cell update -> sc-store h -> arrival tree.
__launch_bounds__(TPB, 4)
__global__ void lstm_fused_k(const float* __restrict__ x,
                             const float* __restrict__ h0,
                             const float* __restrict__ c0,
                             const float* __restrict__ Wih,
                             const float* __restrict__ Whh,
                             const float* __restrict__ bih,
                             const float* __restrict__ bhh,
                             const float* __restrict__ fcw,
                             const float* __restrict__ fcb,
                             float* __restrict__ out,
                             float* __restrict__ hbuf,  // ws: [NLAYER*HDIM]
                             unsigned* __restrict__ g1, // ws: [(l*NGRP+g)*16]
                             unsigned* __restrict__ rt) // ws: [l*16]
{
    __shared__ float wlds[4][2][1024];  // 32 KiB: per-wave 2 rows x half-K
    __shared__ float sg[8];
    __shared__ float part[4];

    const int tid   = threadIdx.x;
    const int lane  = tid & 63;
    const int wave  = tid >> 6;     // gate index (i,f,g,o)
    const int blk   = blockIdx.x;
    const int cell0 = blk * 2;
    const int grp   = blk >> 5;     // 32 groups of 32

    for (int l = 0; l < NLAYER; ++l) {
        const float* Wi   = Wih + (size_t)l * 4 * HDIM * HDIM;
        const float* Wh   = Whh + (size_t)l * 4 * HDIM * HDIM;
        const int    row0 = wave * HDIM + cell0;
        const float* rowA = Wi + (size_t)row0 * HDIM;
        const float* rowB = Wi + (size_t)(row0 + 1) * HDIM;

        float4 h[8];
        if (l == 0) {
            // x is an input: plain cached loads, no wait, no staging
#pragma unroll
            for (int it = 0; it < 8; ++it) h[it] = ((const float4*)x)[it * 64 + lane];
        } else {
            // ---- stage half-K of both rows into LDS (pre-wait, async DMA)
#pragma unroll
            for (int c = 0; c < 4; ++c) {
                __builtin_amdgcn_global_load_lds((glbu_t*)(rowA + c * 256 + lane * 4),
                                                 (ldsu_t*)&wlds[wave][0][c * 256], 16, 0, 0);
                __builtin_amdgcn_global_load_lds((glbu_t*)(rowB + c * 256 + lane * 4),
                                                 (ldsu_t*)&wlds[wave][1][c * 256], 16, 0, 0);
            }
            // ---- wait for h_{l-1}; staging streams at HBM rate meanwhile
            if (tid == 0) {
                while (sc_load_u32(&rt[(l - 1) * 16]) < (unsigned)NGRP)
                    __builtin_amdgcn_s_sleep(32);
            }
            __syncthreads();
            // ---- fresh h from LLC (no cache invalidation anywhere)
            sc_load_h8(hbuf + (size_t)(l - 1) * HDIM, lane, h);
        }

        float acc0 = 0.0f, acc1 = 0.0f;
        if (l == 0) {
            const float4* r0 = (const float4*)rowA;
            const float4* r1 = (const float4*)rowB;
#pragma unroll
            for (int it = 0; it < 8; ++it) {
                const float4 a0 = r0[it * 64 + lane];
                const float4 a1 = r1[it * 64 + lane];
                DOT4(acc0, a0, h[it]);
                DOT4(acc1, a1, h[it]);
            }
        } else {
            const float4* wl0 = (const float4*)wlds[wave][0];
            const float4* wl1 = (const float4*)wlds[wave][1];
#pragma unroll
            for (int it = 0; it < 4; ++it) {  // half-K from LDS (prefetched)
                const float4 a0 = wl0[it * 64 + lane];
                const float4 a1 = wl1[it * 64 + lane];
                DOT4(acc0, a0, h[it]);
                DOT4(acc1, a1, h[it]);
            }
            const float4* r0 = (const float4*)rowA;
            const float4* r1 = (const float4*)rowB;
#pragma unroll
            for (int it = 4; it < 8; ++it) {  // half-K streamed from global
                const float4 a0 = r0[it * 64 + lane];
                const float4 a1 = r1[it * 64 + lane];
                DOT4(acc0, a0, h[it]);
                DOT4(acc1, a1, h[it]);
            }
        }

        // W_hh: exact per-chunk skip (h_prev==0 here -> no weight traffic)
        {
            const float4* hp4 = (const float4*)(h0 + l * HDIM);
            const float4* q0r = (const float4*)(Wh + (size_t)row0 * HDIM);
            const float4* q1r = (const float4*)(Wh + (size_t)(row0 + 1) * HDIM);
#pragma unroll
            for (int it = 0; it < 8; ++it) {
                const float4 p = hp4[it * 64 + lane];
                if (p.x != 0.0f || p.y != 0.0f || p.z != 0.0f || p.w != 0.0f) {
                    const float4 q0 = q0r[it * 64 + lane];
                    const float4 q1 = q1r[it * 64 + lane];
                    DOT4(acc0, q0, p);
                    DOT4(acc1, q1, p);
                }
            }
        }

#pragma unroll
        for (int off = 32; off > 0; off >>= 1) {
            acc0 += __shfl_down(acc0, off, 64);
            acc1 += __shfl_down(acc1, off, 64);
        }
        if (lane == 0) {
            const float* bi = bih + (size_t)l * 4 * HDIM;
            const float* bh = bhh + (size_t)l * 4 * HDIM;
            sg[wave * 2 + 0] = acc0 + bi[row0] + bh[row0];
            sg[wave * 2 + 1] = acc1 + bi[row0 + 1] + bh[row0 + 1];
        }
        __syncthreads();

        if (tid < 2) {
            const float iv = sg[0 + tid];
            const float fv = sg[2 + tid];
            const float gv = sg[4 + tid];
            const float ov = sg[6 + tid];
            const float cpv = c0[l * HDIM + cell0 + tid];
            const float cv = sigmoidf_(fv) * cpv + sigmoidf_(iv) * tanhf(gv);
            // sc store (reaches LLC; trailing vmcnt(0) inside = completion)
            sc_store_f(&hbuf[(size_t)l * HDIM + cell0 + tid],
                       sigmoidf_(ov) * tanhf(cv));
        }
        if (tid == 0) {  // arrival tree: 32-wide fan-in, no hot line
            unsigned old = __hip_atomic_fetch_add(&g1[(l * NGRP + grp) * 16], 1u,
                                                  __ATOMIC_RELAXED, __HIP_MEMORY_SCOPE_AGENT);
            if (old == (unsigned)(GRPSZ - 1))
                __hip_atomic_fetch_add(&rt[l * 16], 1u,
                                       __ATOMIC_RELAXED, __HIP_MEMORY_SCOPE_AGENT);
        }
    }

    // ---- FC epilogue: out[blk] = fcw[blk,:] @ h3 + fcb[blk]
    {
        const float* fcrow = fcw + (size_t)blk * HDIM;
        float* wf = &wlds[0][0][0];  // reuse 8 KiB of staging LDS
        // stage the fc row (pre-wait): wave w stages chunks 2w, 2w+1
#pragma unroll
        for (int c = 0; c < 2; ++c) {
            const int ch = 2 * wave + c;
            __builtin_amdgcn_global_load_lds((glbu_t*)(fcrow + ch * 256 + lane * 4),
                                             (ldsu_t*)&wf[ch * 256], 16, 0, 0);
        }
        if (tid == 0) {
            while (sc_load_u32(&rt[(NLAYER - 1) * 16]) < (unsigned)NGRP)
                __builtin_amdgcn_s_sleep(32);
        }
        __syncthreads();

        float4 ha, hb;
        sc_load_h2(hbuf + (size_t)(NLAYER - 1) * HDIM, tid, ha, hb);
        const float4 fa = ((const float4*)wf)[tid];
        const float4 fb = ((const float4*)wf)[tid + 256];
        float acc = 0.0f;
        DOT4(acc, fa, ha);
        DOT4(acc, fb, hb);
#pragma unroll
        for (int off = 32; off > 0; off >>= 1) acc += __shfl_down(acc, off, 64);
        if (lane == 0) part[wave] = acc;
        __syncthreads();
        if (tid == 0)
            out[blk] = part[0] + part[1] + part[2] + part[3] + fcb[blk];
    }
}

// ---------------- Fallback path (proven 58 us, R1) ----------------
__launch_bounds__(256)
__global__ void lstm_layer_k(const float* __restrict__ Wi,
                             const float* __restrict__ Wh,
                             const float* __restrict__ bi,
                             const float* __restrict__ bh,
                             const float* __restrict__ hin,
                             const float* __restrict__ hprev,
                             const float* __restrict__ cprev,
                             float* __restrict__ hout)
{
    __shared__ float4 sh_in[HDIM / 4];
    __shared__ float  sgates[8];
    __shared__ int    nzflag;

    const int tid = threadIdx.x;
    if (tid == 0) nzflag = 0;
    __syncthreads();

    int nz = 0;
#pragma unroll
    for (int i = 0; i < 2; ++i) {
        const int idx = tid + i * 256;
        sh_in[idx] = ((const float4*)hin)[idx];
        float4 p = ((const float4*)hprev)[idx];
        if (p.x != 0.0f || p.y != 0.0f || p.z != 0.0f || p.w != 0.0f) nz = 1;
    }
    if (nz) nzflag = 1;
    __syncthreads();
    const int any_prev = nzflag;

    const int lane = tid & 63;
    const int wave = tid >> 6;
    const int cell0 = blockIdx.x * 2;
    const int row0 = wave * HDIM + cell0;

    const float4* r0 = (const float4*)(Wi + (size_t)row0 * HDIM);
    const float4* r1 = (const float4*)(Wi + (size_t)(row0 + 1) * HDIM);

    float acc0 = 0.0f, acc1 = 0.0f;
#pragma unroll
    for (int it = 0; it < 8; ++it) {
        const int idx = it * 64 + lane;
        const float4 a0 = r0[idx];
        const float4 a1 = r1[idx];
        const float4 hv = sh_in[idx];
        DOT4(acc0, a0, hv);
        DOT4(acc1, a1, hv);
    }

    if (any_prev) {
        const float4* q0 = (const float4*)(Wh + (size_t)row0 * HDIM);
        const float4* q1 = (const float4*)(Wh + (size_t)(row0 + 1) * HDIM);
        const float4* pv4 = (const float4*)hprev;
#pragma unroll
        for (int it = 0; it < 8; ++it) {
            const int idx = it * 64 + lane;
            const float4 a0 = q0[idx];
            const float4 a1 = q1[idx];
            const float4 pv = pv4[idx];
            DOT4(acc0, a0, pv);
            DOT4(acc1, a1, pv);
        }
    }

#pragma unroll
    for (int off = 32; off > 0; off >>= 1) {
        acc0 += __shfl_down(acc0, off, 64);
        acc1 += __shfl_down(acc1, off, 64);
    }
    if (lane == 0) {
        sgates[wave * 2 + 0] = acc0 + bi[row0] + bh[row0];
        sgates[wave * 2 + 1] = acc1 + bi[row0 + 1] + bh[row0 + 1];
    }
    __syncthreads();

    if (tid < 2) {
        const float iv = sgates[0 * 2 + tid];
        const float fv = sgates[1 * 2 + tid];
        const float gv = sgates[2 * 2 + tid];
        const float ov = sgates[3 * 2 + tid];
        const float cp = cprev[cell0 + tid];
        const float cv = sigmoidf_(fv) * cp + sigmoidf_(iv) * tanhf(gv);
        hout[cell0 + tid] = sigmoidf_(ov) * tanhf(cv);
    }
}

__launch_bounds__(256)
__global__ void fc_k(const float* __restrict__ W, const float* __restrict__ b,
                     const float* __restrict__ h, float* __restrict__ out)
{
    __shared__ float4 sh[HDIM / 4];
    const int tid = threadIdx.x;
#pragma unroll
    for (int i = 0; i < 2; ++i)
        sh[tid + i * 256] = ((const float4*)h)[tid + i * 256];
    __syncthreads();

    const int lane = tid & 63;
    const int wave = tid >> 6;
    const int row = blockIdx.x * 4 + wave;

    const float4* r = (const float4*)(W + (size_t)row * HDIM);
    float acc = 0.0f;
#pragma unroll
    for (int it = 0; it < 8; ++it) {
        const int idx = it * 64 + lane;
        const float4 a = r[idx];
        const float4 hv = sh[idx];
        DOT4(acc, a, hv);
    }
#pragma unroll
    for (int off = 32; off > 0; off >>= 1) acc += __shfl_down(acc, off, 64);
    if (lane == 0) out[row] = acc + b[row];
}

extern "C" void kernel_launch(void* const* d_in, const int* in_sizes, int n_in,
                              void* d_out, int out_size, void* d_ws, size_t ws_size,
                              hipStream_t stream) {
    const float* x   = (const float*)d_in[0];
    const float* h0  = (const float*)d_in[1];
    const float* c0  = (const float*)d_in[2];
    const float* Wih = (const float*)d_in[3];
    const float* Whh = (const float*)d_in[4];
    const float* bih = (const float*)d_in[5];
    const float* bhh = (const float*)d_in[6];
    const float* fcw = (const float*)d_in[7];
    const float* fcb = (const float*)d_in[8];
    float* out = (float*)d_out;

    float*    hbuf = (float*)d_ws;                          // 32 KiB
    unsigned* g1   = (unsigned*)((char*)d_ws + 32 * 1024);  // 8 KiB group ctrs
    unsigned* rt   = (unsigned*)((char*)d_ws + 40 * 1024);  // 256 B roots

    // Zero all counters each call (ws is poisoned once / stale across replays)
    (void)hipMemsetAsync((char*)d_ws + 32 * 1024, 0, 8 * 1024 + 256, stream);

    void* args[] = {(void*)&x, (void*)&h0, (void*)&c0, (void*)&Wih, (void*)&Whh,
                    (void*)&bih, (void*)&bhh, (void*)&fcw, (void*)&fcb,
                    (void*)&out, (void*)&hbuf, (void*)&g1, (void*)&rt};
    hipError_t e = hipLaunchCooperativeKernel((void*)lstm_fused_k,
                                              dim3(NBLK), dim3(TPB),
                                              args, 0, stream);
    if (e != hipSuccess) {
        // Fallback: 5 sequential launches (identical math -> identical output).
        const size_t wstride = (size_t)4 * HDIM * HDIM;
        const int    bstride = 4 * HDIM;
        float* hb0 = hbuf;
        float* hb1 = hbuf + HDIM;
        const float* hin = x;
        float* houts[4] = {hb0, hb1, hb0, hb1};
        for (int l = 0; l < 4; ++l) {
            lstm_layer_k<<<HDIM / 2, 256, 0, stream>>>(
                Wih + (size_t)l * wstride, Whh + (size_t)l * wstride,
                bih + l * bstride, bhh + l * bstride,
                hin, h0 + l * HDIM, c0 + l * HDIM, houts[l]);
            hin = houts[l];
        }
        fc_k<<<DOUT / 4, 256, 0, stream>>>(fcw, fcb, hb1, out);
    }
}